// Round 7
// baseline (384.912 us; speedup 1.0000x reference)
//
#include <hip/hip_runtime.h>

typedef int v4i __attribute__((ext_vector_type(4)));

// ---- d_out layout (floats) --------------------------------------------------
// hidden [0, 8388608) | syn [8388608,16777216) | mem_f/i/g/o 4x4194304 from
// 16777216 | mem_h [33554432, 41943040)
#define OFF_SYN   8388608ull
#define OFF_MEM   16777216ull
#define OFF_MEMH  33554432ull
// scratch (bytes), only inside regions later overwritten by k_gemm-independent
// writers: W digit planes [0, 50331648) (= hidden+part of syn regions),
// spike-i8 x1,x2 [50331648, 67108864) (= rest of syn region),
// spike-i8 x3,x4,h [134217728, 159383552) (= inside mem_h region).
#define AQ01_BYTE  50331648ull
#define AQ234_BYTE 134217728ull
#define A_BYTES    8388608ull

struct PackArgs { const int4* src[5]; int4* dst[5]; };
struct WArgs    { const float* W1[4]; const float* W2[4]; signed char* Wq; };
struct GArgs {
  const signed char* ax[4];
  const signed char* ah;
  const signed char* Wq;
  const float* mem[4];
  const float* b1[4];
  const float* b2[4];
  const float* beta[4];
  const float* thr[4];
  float* out;
};
struct CArgs {
  const float* memo; const float* syn_prev; const float* mem_hidden;
  const float* thr[4]; const float* beta_h; const float* thr_h;
  float* hid; float* syn; float* memh;
};

__device__ __forceinline__ void gload16(const void* gsrc, void* lds) {
  __builtin_amdgcn_global_load_lds(
      (__attribute__((address_space(1))) void*)(gsrc),
      (__attribute__((address_space(3))) void*)(lds), 16, 0, 0);
}

// ---- spikes fp32 (0.0/1.0) -> int8 0/1 -------------------------------------
__global__ __launch_bounds__(256) void k_pack(PackArgs a) {
  unsigned idx = blockIdx.x * 256u + threadIdx.x;   // 5 * 524288 threads
  unsigned arr = idx >> 19;
  unsigned off = idx & 524287u;
  const int4* s = a.src[arr] + (size_t)off * 4;
  int4 v0 = s[0], v1 = s[1], v2 = s[2], v3 = s[3];
  union { signed char c[16]; int4 v; } u;
  u.c[0]=(signed char)(v0.x!=0); u.c[1]=(signed char)(v0.y!=0);
  u.c[2]=(signed char)(v0.z!=0); u.c[3]=(signed char)(v0.w!=0);
  u.c[4]=(signed char)(v1.x!=0); u.c[5]=(signed char)(v1.y!=0);
  u.c[6]=(signed char)(v1.z!=0); u.c[7]=(signed char)(v1.w!=0);
  u.c[8]=(signed char)(v2.x!=0); u.c[9]=(signed char)(v2.y!=0);
  u.c[10]=(signed char)(v2.z!=0); u.c[11]=(signed char)(v2.w!=0);
  u.c[12]=(signed char)(v3.x!=0); u.c[13]=(signed char)(v3.y!=0);
  u.c[14]=(signed char)(v3.z!=0); u.c[15]=(signed char)(v3.w!=0);
  a.dst[arr][off] = u.v;
}

// ---- weights -> 3 balanced base-256 digit planes at scale 2^28 --------------
// w ~ U(-b,b), b = 1/sqrt(2048) = 0.0221 -> |q| <= 5.94e6 fits 3 digits.
// (2 digits at scale 2^20 would cut MFMA work 33% but raises our enc error to
// ~8e-6 ~ np's own noise -> expected gate-count flips -> hidden-spike flip
// risk (absmax 1.0). Keep 3.)
__global__ __launch_bounds__(256) void k_wdig(WArgs a) {
  unsigned idx = blockIdx.x * 256u + threadIdx.x;   // 4*1024*1024 threads
  unsigned g  = idx >> 20;
  unsigned n  = (idx >> 10) & 1023u;
  unsigned kk = (idx & 1023u) << 2;                 // k, multiple of 4
  const float* src = (kk < 2048u) ? (a.W1[g] + (size_t)n * 2048 + kk)
                                  : (a.W2[g] + (size_t)n * 2048 + (kk - 2048u));
  float4 w = *(const float4*)src;
  float wv[4] = {w.x, w.y, w.z, w.w};
  union { signed char c[4]; int i; } u0, u1, u2;
  #pragma unroll
  for (int e = 0; e < 4; ++e) {
    long long q = llrint((double)wv[e] * 268435456.0);  // 2^28
    long long r0 = ((q + 128) & 255) - 128; q = (q - r0) / 256;
    long long r1 = ((q + 128) & 255) - 128; q = (q - r1) / 256;
    u0.c[e] = (signed char)r0; u1.c[e] = (signed char)r1; u2.c[e] = (signed char)q;
  }
  size_t gb = (size_t)g * 3ull * 1024ull * 4096ull;
  size_t base = (size_t)n * 4096 + kk;
  *(int*)(a.Wq + gb + 0ull * 4194304ull + base) = u0.i;
  *(int*)(a.Wq + gb + 1ull * 4194304ull + base) = u1.i;
  *(int*)(a.Wq + gb + 2ull * 4194304ull + base) = u2.i;
}

// ---- exact i8 GEMM: per gate enc = [x|h] . W^T (3 digit planes) -------------
// Round-7: m201-style fine-phase schedule. Block 128(M) x 128(N), BK=64,
// 512 threads = 8 waves as 2(M) x 4(N), wave tile 64x32, mfma_i32_16x16x64_i8,
// acc 96 regs (AGPR-resident). Ring-4 LDS (128 KiB, 1 block/CU = 2 waves/SIMD,
// same occupancy as R5's 2x4-wave blocks). Per K-tile t: TWO phases
//   P1: 7 ds_read (av[0..3], bv[*][0]) + 2 stage-gloads(t+2)
//       -> s_barrier -> lgkmcnt(0) -> setprio1 -> 12 MFMA (ni=0) -> barrier
//   P2: 3 ds_read (bv[*][1]) + 2 stage-gloads(t+2)
//       -> s_barrier -> lgkmcnt(0) -> setprio1 -> 12 MFMA (ni=1)
//       -> s_waitcnt vmcnt(4) -> s_barrier      // counted, never 0 in loop
// Depth-2 prefetch: stage(t+2) issued during tile t; vmcnt(4) at end of tile t
// waits only stage(t+1) (a full tile of slack); stage(t+2)'s 4 stay in flight.
// Slot safety: stage(t+2) overwrites slot (t-2)&3, whose reads completed
// before the end-of-(t-2) barrier (MFMA operand deps force lgkm completion
// before issue) - two barriers before the overwrite is issued.
// Rationale: R5 (BK=128 coarse 2-buf) = 223us/40% MfmaUtil with ~55% of each
// step idle at the once-per-tile lockstep drain; R6 (coarse counted-vmcnt at
// BK=64) = 291us — coarse split without fine interleave hurts (guide m196).
// __launch_bounds__ 2nd arg MUST stay 2: capping VGPR at 128 spills acc ->
// 1.67 GB scratch WRITE_SIZE, 3.4x slower (measured round 2).
__global__ __launch_bounds__(512, 2) void k_gemm(GArgs a) {
  __shared__ __align__(16) signed char As[4][128 * 64];        // 32 KiB
  __shared__ __align__(16) signed char Bs[4][3][128 * 64];     // 96 KiB
  const int tid = threadIdx.x;
  const int w = tid >> 6, l = tid & 63;
  const int wr = w >> 2, wc = w & 3;
  const int g = blockIdx.z, mt = blockIdx.y, nt = blockIdx.x;
  const int lr = l >> 2;   // 0..15 (staging row-within-segment)
  const int lk = l & 3;    // 0..3  (staging 16B chunk)

  v4i acc[3][4][2];
  v4i zero = {0, 0, 0, 0};
  #pragma unroll
  for (int d = 0; d < 3; ++d)
    #pragma unroll
    for (int mi = 0; mi < 4; ++mi)
      #pragma unroll
      for (int ni = 0; ni < 2; ++ni) acc[d][mi][ni] = zero;

  const signed char* Wg = a.Wq + (size_t)g * 3ull * 4194304ull
                               + (size_t)(nt * 128) * 4096ull;

  // Staging for K-tile t (K0=t*64), split across the two phases.
  // LDS[r][c] holds global chunk c ^ ((r>>1)&3): pre-swizzled source, linear
  // dest (wave-uniform base + lane*16, as global_load_lds requires; measured
  // 0 bank conflicts with the matching read-side XOR).
  auto stageP1 = [&](int buf, int t) {   // 2 gloads: A seg w, B plane0 seg w
    int K0 = t * 64;
    const signed char* Ab; int kl;
    if (K0 < 2048) { Ab = a.ax[g]; kl = K0; } else { Ab = a.ah; kl = K0 - 2048; }
    int rl = (w << 4) + lr;
    int sw = (rl >> 1) & 3;
    gload16(Ab + (size_t)(mt * 128 + rl) * 2048 + kl + ((lk ^ sw) << 4),
            &As[buf][(w << 4) * 64]);
    gload16(Wg + (size_t)rl * 4096ull + K0 + ((lk ^ sw) << 4),
            &Bs[buf][0][(w << 4) * 64]);
  };
  auto stageP2 = [&](int buf, int t) {   // 2 gloads: B planes 1,2 seg w
    int K0 = t * 64;
    int rl = (w << 4) + lr;
    int sw = (rl >> 1) & 3;
    #pragma unroll
    for (int d = 1; d < 3; ++d)
      gload16(Wg + (size_t)d * 4194304ull + (size_t)rl * 4096ull + K0
                 + ((lk ^ sw) << 4),
              &Bs[buf][d][(w << 4) * 64]);
  };

  auto step = [&](int t, bool pf, bool drain) {
    const int cur = t & 3;
    v4i av[4];
    v4i bv[3][2];
    // ---- P1: reads for ni=0 cluster (+av, reused by P2) ----
    #pragma unroll
    for (int mi = 0; mi < 4; ++mi) {
      int ar = wr * 64 + mi * 16 + (l & 15);
      int kg = (l >> 4) ^ ((ar >> 1) & 3);
      av[mi] = *(const v4i*)&As[cur][ar * 64 + kg * 16];
    }
    #pragma unroll
    for (int d = 0; d < 3; ++d) {
      int br = wc * 32 + (l & 15);
      int kg = (l >> 4) ^ ((br >> 1) & 3);
      bv[d][0] = *(const v4i*)&Bs[cur][d][br * 64 + kg * 16];
    }
    if (pf) stageP1((t + 2) & 3, t + 2);
    __builtin_amdgcn_sched_barrier(0);
    __builtin_amdgcn_s_barrier();
    asm volatile("s_waitcnt lgkmcnt(0)" ::: "memory");
    __builtin_amdgcn_sched_barrier(0);
    __builtin_amdgcn_s_setprio(1);
    #pragma unroll
    for (int d = 0; d < 3; ++d)
      #pragma unroll
      for (int mi = 0; mi < 4; ++mi)
        acc[d][mi][0] = __builtin_amdgcn_mfma_i32_16x16x64_i8(
            av[mi], bv[d][0], acc[d][mi][0], 0, 0, 0);
    __builtin_amdgcn_s_setprio(0);
    __builtin_amdgcn_sched_barrier(0);
    __builtin_amdgcn_s_barrier();
    // ---- P2: reads for ni=1 cluster ----
    #pragma unroll
    for (int d = 0; d < 3; ++d) {
      int br = wc * 32 + 16 + (l & 15);
      int kg = (l >> 4) ^ ((br >> 1) & 3);
      bv[d][1] = *(const v4i*)&Bs[cur][d][br * 64 + kg * 16];
    }
    if (pf) stageP2((t + 2) & 3, t + 2);
    __builtin_amdgcn_sched_barrier(0);
    __builtin_amdgcn_s_barrier();
    asm volatile("s_waitcnt lgkmcnt(0)" ::: "memory");
    __builtin_amdgcn_sched_barrier(0);
    __builtin_amdgcn_s_setprio(1);
    #pragma unroll
    for (int d = 0; d < 3; ++d)
      #pragma unroll
      for (int mi = 0; mi < 4; ++mi)
        acc[d][mi][1] = __builtin_amdgcn_mfma_i32_16x16x64_i8(
            av[mi], bv[d][1], acc[d][mi][1], 0, 0, 0);
    __builtin_amdgcn_s_setprio(0);
    __builtin_amdgcn_sched_barrier(0);
    if (drain) asm volatile("s_waitcnt vmcnt(0)" ::: "memory");
    else       asm volatile("s_waitcnt vmcnt(4)" ::: "memory");
    __builtin_amdgcn_s_barrier();
  };

  // prologue: tiles 0 and 1 staged; vmcnt(4) -> tile 0 landed (tile 1 in flight)
  stageP1(0, 0); stageP2(0, 0);
  stageP1(1, 1); stageP2(1, 1);
  asm volatile("s_waitcnt vmcnt(4)" ::: "memory");
  __builtin_amdgcn_s_barrier();
  for (int t = 0; t < 62; ++t) step(t, true, false);
  step(62, false, true);    // drains stage(63) (only 4 in flight)
  step(63, false, true);    // no-op drain

  // epilogue: recombine digits exactly in f64, leaky step, write mem_new
  const float* b1 = a.b1[g];
  const float* b2 = a.b2[g];
  const float* memg = a.mem[g];
  float* outg = a.out + (size_t)g * 4194304ull;
  double beta = fmin(fmax((double)(*a.beta[g]), 0.0), 1.0);
  double thr = (double)(*a.thr[g]);
  #pragma unroll
  for (int mi = 0; mi < 4; ++mi)
    #pragma unroll
    for (int ni = 0; ni < 2; ++ni) {
      int m0 = mt * 128 + wr * 64 + mi * 16 + ((l >> 4) << 2);
      int n  = nt * 128 + wc * 32 + ni * 16 + (l & 15);
      double bsum = (double)b1[n] + (double)b2[n];
      #pragma unroll
      for (int j = 0; j < 4; ++j) {
        double e = (double)acc[2][mi][ni][j] * 65536.0
                 + (double)acc[1][mi][ni][j] * 256.0
                 + (double)acc[0][mi][ni][j];
        double enc = e * (1.0 / 268435456.0) + bsum;
        size_t o = (size_t)(m0 + j) * 1024 + n;
        double mp = (double)memg[o];
        double reset = (mp - thr > 0.0) ? 1.0 : 0.0;
        double mn = beta * mp + enc - reset * thr;
        outg[o] = (float)mn;
      }
    }
}

// ---- finalize: counts -> f,i,g,o -> syn, mem_h, hidden (all f64) ------------
__global__ __launch_bounds__(256) void k_fin(CArgs a) {
  const int b = blockIdx.x, tid = threadIdx.x;
  const int w = tid >> 6, l = tid & 63;
  __shared__ int scnt[4];
  __shared__ double sval[3];
  const float* mg = a.memo + (size_t)w * 4194304ull + (size_t)b * 1024;
  const float thrw = *a.thr[w];
  int cnt = 0;
  #pragma unroll
  for (int p = 0; p < 16; ++p) {
    float v = mg[l + p * 64];
    cnt += ((v - thrw) > 0.0f) ? 1 : 0;
  }
  #pragma unroll
  for (int off = 32; off; off >>= 1) cnt += __shfl_down(cnt, off, 64);
  if (l == 0) scnt[w] = cnt;
  __syncthreads();
  if (tid == 0) {
    double mf = scnt[0] * (1.0 / 1024.0);
    double mi = scnt[1] * (1.0 / 1024.0);
    double mgv = scnt[2] * (1.0 / 1024.0);
    double mo = scnt[3] * (1.0 / 1024.0);
    double f  = 1.0 / (1.0 + exp(-mf));
    double ii = 1.0 / (1.0 + exp(-mi));
    double gv = tanh(mgv);
    double oo = 1.0 / (1.0 + exp(-mo));
    sval[0] = f; sval[1] = ii * gv; sval[2] = oo;
  }
  __syncthreads();
  const double f = sval[0], ig = sval[1], oo = sval[2];
  const double bh = fmin(fmax((double)(*a.beta_h), 0.0), 1.0);
  const double th = (double)(*a.thr_h);
  const size_t rb = (size_t)b * 2048;
  for (int j = tid; j < 2048; j += 256) {
    double s = f * (double)a.syn_prev[rb + j] + ig;
    double mp = (double)a.mem_hidden[rb + j];
    double reset = (mp - th > 0.0) ? 1.0 : 0.0;
    double mh = bh * mp + oo * tanh(s) - reset * th;
    a.syn[rb + j] = (float)s;
    a.memh[rb + j] = (float)mh;
    a.hid[rb + j] = ((mh - th) > 0.0) ? 1.0f : 0.0f;
  }
}

extern "C" void kernel_launch(void* const* d_in, const int* in_sizes, int n_in,
                              void* d_out, int out_size, void* d_ws, size_t ws_size,
                              hipStream_t stream) {
  (void)in_sizes; (void)n_in; (void)out_size; (void)d_ws; (void)ws_size;
  float* out = (float*)d_out;
  signed char* base8 = (signed char*)d_out;

  PackArgs pa;
  for (int i = 0; i < 5; ++i) {
    pa.src[i] = (const int4*)d_in[i];
    pa.dst[i] = (int4*)(base8 + (i < 2 ? (AQ01_BYTE + (size_t)i * A_BYTES)
                                       : (AQ234_BYTE + (size_t)(i - 2) * A_BYTES)));
  }
  WArgs wa; wa.Wq = base8;
  for (int g = 0; g < 4; ++g) {
    wa.W1[g] = (const float*)d_in[11 + 4 * g];
    wa.W2[g] = (const float*)d_in[13 + 4 * g];
  }
  GArgs ga;
  for (int g = 0; g < 4; ++g) {
    ga.ax[g]   = (const signed char*)pa.dst[g];
    ga.mem[g]  = (const float*)d_in[6 + g];
    ga.b1[g]   = (const float*)d_in[12 + 4 * g];
    ga.b2[g]   = (const float*)d_in[14 + 4 * g];
    ga.beta[g] = (const float*)d_in[27 + 2 * g];
    ga.thr[g]  = (const float*)d_in[28 + 2 * g];
  }
  ga.ah = (const signed char*)pa.dst[4];
  ga.Wq = base8;
  ga.out = out + OFF_MEM;

  CArgs ca;
  ca.memo = out + OFF_MEM;
  ca.syn_prev = (const float*)d_in[5];
  ca.mem_hidden = (const float*)d_in[10];
  for (int g = 0; g < 4; ++g) ca.thr[g] = (const float*)d_in[28 + 2 * g];
  ca.beta_h = (const float*)d_in[35];
  ca.thr_h = (const float*)d_in[36];
  ca.hid = out;
  ca.syn = out + OFF_SYN;
  ca.memh = out + OFF_MEMH;

  k_pack<<<10240, 256, 0, stream>>>(pa);
  k_wdig<<<16384, 256, 0, stream>>>(wa);
  k_gemm<<<dim3(8, 32, 4), 512, 0, stream>>>(ga);
  k_fin<<<4096, 256, 0, stream>>>(ca);
}

// Round 8
// 381.938 us; speedup vs baseline: 1.0078x; 1.0078x over previous
//
#include <hip/hip_runtime.h>

typedef int v4i __attribute__((ext_vector_type(4)));

// ---- d_out layout (floats) --------------------------------------------------
#define OFF_SYN   8388608ull
#define OFF_MEM   16777216ull
#define OFF_MEMH  33554432ull
#define AQ01_BYTE  50331648ull
#define AQ234_BYTE 134217728ull
#define A_BYTES    8388608ull

struct PackArgs { const int4* src[5]; int4* dst[5]; };
struct WArgs    { const float* W1[4]; const float* W2[4]; signed char* Wq; };
struct GArgs {
  const signed char* ax[4];
  const signed char* ah;
  const signed char* Wq;
  const float* mem[4];
  const float* b1[4];
  const float* b2[4];
  const float* beta[4];
  const float* thr[4];
  float* out;
};
struct CArgs {
  const float* memo; const float* syn_prev; const float* mem_hidden;
  const float* thr[4]; const float* beta_h; const float* thr_h;
  float* hid; float* syn; float* memh;
};

__device__ __forceinline__ void gload16(const void* gsrc, void* lds) {
  __builtin_amdgcn_global_load_lds(
      (__attribute__((address_space(1))) void*)(gsrc),
      (__attribute__((address_space(3))) void*)(lds), 16, 0, 0);
}

// ---- spikes fp32 (0.0/1.0) -> int8 0/1 -------------------------------------
__global__ __launch_bounds__(256) void k_pack(PackArgs a) {
  unsigned idx = blockIdx.x * 256u + threadIdx.x;   // 5 * 524288 threads
  unsigned arr = idx >> 19;
  unsigned off = idx & 524287u;
  const int4* s = a.src[arr] + (size_t)off * 4;
  int4 v0 = s[0], v1 = s[1], v2 = s[2], v3 = s[3];
  union { signed char c[16]; int4 v; } u;
  u.c[0]=(signed char)(v0.x!=0); u.c[1]=(signed char)(v0.y!=0);
  u.c[2]=(signed char)(v0.z!=0); u.c[3]=(signed char)(v0.w!=0);
  u.c[4]=(signed char)(v1.x!=0); u.c[5]=(signed char)(v1.y!=0);
  u.c[6]=(signed char)(v1.z!=0); u.c[7]=(signed char)(v1.w!=0);
  u.c[8]=(signed char)(v2.x!=0); u.c[9]=(signed char)(v2.y!=0);
  u.c[10]=(signed char)(v2.z!=0); u.c[11]=(signed char)(v2.w!=0);
  u.c[12]=(signed char)(v3.x!=0); u.c[13]=(signed char)(v3.y!=0);
  u.c[14]=(signed char)(v3.z!=0); u.c[15]=(signed char)(v3.w!=0);
  a.dst[arr][off] = u.v;
}

// ---- weights -> 3 balanced base-256 digit planes at scale 2^28 --------------
// w ~ U(-b,b), b = 1/sqrt(2048) = 0.0221 -> |q| <= 5.94e6 fits 3 digits.
// (2 digits at 2^20 would cut MFMA 33% but adds ~8e-6 enc error ~ np's own
// noise level -> changes the spike-flip set -> hidden absmax-1.0 coin flip.)
__global__ __launch_bounds__(256) void k_wdig(WArgs a) {
  unsigned idx = blockIdx.x * 256u + threadIdx.x;   // 4*1024*1024 threads
  unsigned g  = idx >> 20;
  unsigned n  = (idx >> 10) & 1023u;
  unsigned kk = (idx & 1023u) << 2;                 // k, multiple of 4
  const float* src = (kk < 2048u) ? (a.W1[g] + (size_t)n * 2048 + kk)
                                  : (a.W2[g] + (size_t)n * 2048 + (kk - 2048u));
  float4 w = *(const float4*)src;
  float wv[4] = {w.x, w.y, w.z, w.w};
  union { signed char c[4]; int i; } u0, u1, u2;
  #pragma unroll
  for (int e = 0; e < 4; ++e) {
    long long q = llrint((double)wv[e] * 268435456.0);  // 2^28
    long long r0 = ((q + 128) & 255) - 128; q = (q - r0) / 256;
    long long r1 = ((q + 128) & 255) - 128; q = (q - r1) / 256;
    u0.c[e] = (signed char)r0; u1.c[e] = (signed char)r1; u2.c[e] = (signed char)q;
  }
  size_t gb = (size_t)g * 3ull * 1024ull * 4096ull;
  size_t base = (size_t)n * 4096 + kk;
  *(int*)(a.Wq + gb + 0ull * 4194304ull + base) = u0.i;
  *(int*)(a.Wq + gb + 1ull * 4194304ull + base) = u1.i;
  *(int*)(a.Wq + gb + 2ull * 4194304ull + base) = u2.i;
}

// ---- exact i8 GEMM: per gate enc = [x|h] . W^T (3 digit planes) -------------
// Round-8: R5 geometry (128x64 tile, BK=128, 4 waves 2x2, 2 LDS buffers,
// 80 KiB, 2 blocks/CU) + counted vmcnt. Each tile = 2 k-half phases:
//   phase h: s_waitcnt vmcnt(5) (NEVER 0 in loop) ; s_barrier ;
//            10 ds_read (frags of half h) ; stage half h of tile t+1 ;
//            24 MFMA.
// The stage-half waited at step t+1 was issued at step t -> a full interval
// (~2000 cyc) of slack covers both HBM latency AND the gload->LDS write
// retirement queue (the vmcnt(0) inside __syncthreads stalled on that queue
// every step in R5 - the LDS unit is ~65% busy with reads).
// LDS layout [buf][half][row][64B]: each half-stage is gload-linear; stored
// chunk p holds global chunk p ^ ((row>>1)&3) (involution). Bank math: byte =
// row*64 + p*16 -> cluster = (row&1)*4 + p; read pos q^((row>>1)&3) makes
// 16 consecutive rows hit all 8 clusters x2 = 2 lanes/bank (free; measured 0
// conflicts with the equivalent R5 scheme).
// Overwrite safety: stage half h of tile t+1 (issued after step-t barrier)
// targets buf[cur^1][h], last read at step t-1 phase h; those reads completed
// before step t-1's MFMAs consumed them (lgkm operand waits), two barriers
// before the overwriting loads issue (m201-template depth).
// __launch_bounds__ 2nd arg MUST stay 2: capping VGPR at 128 spills acc ->
// 1.67 GB scratch WRITE_SIZE, 3.4x slower (measured round 2).
__global__ __launch_bounds__(256, 2) void k_gemm(GArgs a) {
  __shared__ __align__(16) signed char As[2][2][128 * 64];    // 32 KiB
  __shared__ __align__(16) signed char Bs[2][3][2][64 * 64];  // 48 KiB
  const int tid = threadIdx.x;
  const int w = tid >> 6, l = tid & 63;
  const int wr = w >> 1, wc = w & 1;
  const int g = blockIdx.z, mt = blockIdx.y, nt = blockIdx.x;

  v4i acc[3][4][2];
  v4i zero = {0, 0, 0, 0};
  #pragma unroll
  for (int d = 0; d < 3; ++d)
    #pragma unroll
    for (int mi = 0; mi < 4; ++mi)
      #pragma unroll
      for (int ni = 0; ni < 2; ++ni) acc[d][mi][ni] = zero;

  const signed char* Wg = a.Wq + (size_t)g * 3ull * 4194304ull
                               + (size_t)(nt * 64) * 4096ull;

  // stage k-half h of tile t into buf (5 gload16/wave: 2 A + 3 B)
  auto stage_half = [&](int buf, int t, int h) {
    int K0 = t * 128 + h * 64;
    const signed char* Ab; int kl;
    if (K0 < 2048) { Ab = a.ax[g]; kl = K0; } else { Ab = a.ah; kl = K0 - 2048; }
    int lrow = l >> 2;            // 0..15 within segment
    int p    = l & 3;             // stored chunk position
    #pragma unroll
    for (int c = 0; c < 2; ++c) {
      int r0 = w * 32 + c * 16;
      int row = r0 + lrow;
      int cg = p ^ ((row >> 1) & 3);
      gload16(Ab + (size_t)(mt * 128 + row) * 2048 + kl + (cg << 4),
              &As[buf][h][r0 * 64]);
    }
    #pragma unroll
    for (int c = 0; c < 3; ++c) {
      int d = c;                  // plane; each wave stages segment w of it
      int row = (w << 4) + lrow;
      int cg = p ^ ((row >> 1) & 3);
      gload16(Wg + (size_t)d * 4194304ull + (size_t)row * 4096ull + K0
                 + (cg << 4),
              &Bs[buf][d][h][(w << 4) * 64]);
    }
  };

  // one k-half phase of step t
  auto phase = [&](int t, int h, bool pf, bool drain) {
    if (drain) asm volatile("s_waitcnt vmcnt(0)" ::: "memory");
    else       asm volatile("s_waitcnt vmcnt(5)" ::: "memory");
    __builtin_amdgcn_s_barrier();
    __builtin_amdgcn_sched_barrier(0);
    const int cur = t & 1;
    v4i av[4];
    v4i bv[3][2];
    #pragma unroll
    for (int mi = 0; mi < 4; ++mi) {
      int ar = wr * 64 + mi * 16 + (l & 15);
      int p = (l >> 4) ^ ((ar >> 1) & 3);
      av[mi] = *(const v4i*)&As[cur][h][ar * 64 + p * 16];
    }
    #pragma unroll
    for (int d = 0; d < 3; ++d)
      #pragma unroll
      for (int ni = 0; ni < 2; ++ni) {
        int br = wc * 32 + ni * 16 + (l & 15);
        int p = (l >> 4) ^ ((br >> 1) & 3);
        bv[d][ni] = *(const v4i*)&Bs[cur][d][h][br * 64 + p * 16];
      }
    if (pf) stage_half(cur ^ 1, t + 1, h);
    __builtin_amdgcn_sched_barrier(0);
    __builtin_amdgcn_s_setprio(1);
    #pragma unroll
    for (int d = 0; d < 3; ++d)
      #pragma unroll
      for (int mi = 0; mi < 4; ++mi)
        #pragma unroll
        for (int ni = 0; ni < 2; ++ni)
          acc[d][mi][ni] = __builtin_amdgcn_mfma_i32_16x16x64_i8(
              av[mi], bv[d][ni], acc[d][mi][ni], 0, 0, 0);
    __builtin_amdgcn_s_setprio(0);
    __builtin_amdgcn_sched_barrier(0);
  };

  // prologue: both halves of tile 0 (10 loads in flight)
  stage_half(0, 0, 0);
  stage_half(0, 0, 1);
  for (int t = 0; t < 31; ++t) {
    phase(t, 0, true, false);   // vmcnt(5): retires sA(t), leaves sB(t)
    phase(t, 1, true, false);   // vmcnt(5): retires sB(t), leaves sA(t+1)
  }
  phase(31, 0, false, false);
  phase(31, 1, false, true);    // final drain

  // epilogue: recombine digits exactly in f64, leaky step, write mem_new
  const float* b1 = a.b1[g];
  const float* b2 = a.b2[g];
  const float* memg = a.mem[g];
  float* outg = a.out + (size_t)g * 4194304ull;
  double beta = fmin(fmax((double)(*a.beta[g]), 0.0), 1.0);
  double thr = (double)(*a.thr[g]);
  #pragma unroll
  for (int mi = 0; mi < 4; ++mi)
    #pragma unroll
    for (int ni = 0; ni < 2; ++ni) {
      int m0 = mt * 128 + wr * 64 + mi * 16 + ((l >> 4) << 2);
      int n  = nt * 64 + wc * 32 + ni * 16 + (l & 15);
      double bsum = (double)b1[n] + (double)b2[n];
      #pragma unroll
      for (int j = 0; j < 4; ++j) {
        double e = (double)acc[2][mi][ni][j] * 65536.0
                 + (double)acc[1][mi][ni][j] * 256.0
                 + (double)acc[0][mi][ni][j];
        double enc = e * (1.0 / 268435456.0) + bsum;
        size_t o = (size_t)(m0 + j) * 1024 + n;
        double mp = (double)memg[o];
        double reset = (mp - thr > 0.0) ? 1.0 : 0.0;
        double mn = beta * mp + enc - reset * thr;
        outg[o] = (float)mn;
      }
    }
}

// ---- finalize: counts -> f,i,g,o -> syn, mem_h, hidden (all f64) ------------
__global__ __launch_bounds__(256) void k_fin(CArgs a) {
  const int b = blockIdx.x, tid = threadIdx.x;
  const int w = tid >> 6, l = tid & 63;
  __shared__ int scnt[4];
  __shared__ double sval[3];
  const float* mg = a.memo + (size_t)w * 4194304ull + (size_t)b * 1024;
  const float thrw = *a.thr[w];
  int cnt = 0;
  #pragma unroll
  for (int p = 0; p < 16; ++p) {
    float v = mg[l + p * 64];
    cnt += ((v - thrw) > 0.0f) ? 1 : 0;
  }
  #pragma unroll
  for (int off = 32; off; off >>= 1) cnt += __shfl_down(cnt, off, 64);
  if (l == 0) scnt[w] = cnt;
  __syncthreads();
  if (tid == 0) {
    double mf = scnt[0] * (1.0 / 1024.0);
    double mi = scnt[1] * (1.0 / 1024.0);
    double mgv = scnt[2] * (1.0 / 1024.0);
    double mo = scnt[3] * (1.0 / 1024.0);
    double f  = 1.0 / (1.0 + exp(-mf));
    double ii = 1.0 / (1.0 + exp(-mi));
    double gv = tanh(mgv);
    double oo = 1.0 / (1.0 + exp(-mo));
    sval[0] = f; sval[1] = ii * gv; sval[2] = oo;
  }
  __syncthreads();
  const double f = sval[0], ig = sval[1], oo = sval[2];
  const double bh = fmin(fmax((double)(*a.beta_h), 0.0), 1.0);
  const double th = (double)(*a.thr_h);
  const size_t rb = (size_t)b * 2048;
  for (int j = tid; j < 2048; j += 256) {
    double s = f * (double)a.syn_prev[rb + j] + ig;
    double mp = (double)a.mem_hidden[rb + j];
    double reset = (mp - th > 0.0) ? 1.0 : 0.0;
    double mh = bh * mp + oo * tanh(s) - reset * th;
    a.syn[rb + j] = (float)s;
    a.memh[rb + j] = (float)mh;
    a.hid[rb + j] = ((mh - th) > 0.0) ? 1.0f : 0.0f;
  }
}

extern "C" void kernel_launch(void* const* d_in, const int* in_sizes, int n_in,
                              void* d_out, int out_size, void* d_ws, size_t ws_size,
                              hipStream_t stream) {
  (void)in_sizes; (void)n_in; (void)out_size; (void)d_ws; (void)ws_size;
  float* out = (float*)d_out;
  signed char* base8 = (signed char*)d_out;

  PackArgs pa;
  for (int i = 0; i < 5; ++i) {
    pa.src[i] = (const int4*)d_in[i];
    pa.dst[i] = (int4*)(base8 + (i < 2 ? (AQ01_BYTE + (size_t)i * A_BYTES)
                                       : (AQ234_BYTE + (size_t)(i - 2) * A_BYTES)));
  }
  WArgs wa; wa.Wq = base8;
  for (int g = 0; g < 4; ++g) {
    wa.W1[g] = (const float*)d_in[11 + 4 * g];
    wa.W2[g] = (const float*)d_in[13 + 4 * g];
  }
  GArgs ga;
  for (int g = 0; g < 4; ++g) {
    ga.ax[g]   = (const signed char*)pa.dst[g];
    ga.mem[g]  = (const float*)d_in[6 + g];
    ga.b1[g]   = (const float*)d_in[12 + 4 * g];
    ga.b2[g]   = (const float*)d_in[14 + 4 * g];
    ga.beta[g] = (const float*)d_in[27 + 2 * g];
    ga.thr[g]  = (const float*)d_in[28 + 2 * g];
  }
  ga.ah = (const signed char*)pa.dst[4];
  ga.Wq = base8;
  ga.out = out + OFF_MEM;

  CArgs ca;
  ca.memo = out + OFF_MEM;
  ca.syn_prev = (const float*)d_in[5];
  ca.mem_hidden = (const float*)d_in[10];
  for (int g = 0; g < 4; ++g) ca.thr[g] = (const float*)d_in[28 + 2 * g];
  ca.beta_h = (const float*)d_in[35];
  ca.thr_h = (const float*)d_in[36];
  ca.hid = out;
  ca.syn = out + OFF_SYN;
  ca.memh = out + OFF_MEMH;

  k_pack<<<10240, 256, 0, stream>>>(pa);
  k_wdig<<<16384, 256, 0, stream>>>(wa);
  k_gemm<<<dim3(16, 32, 4), 256, 0, stream>>>(ga);
  k_fin<<<4096, 256, 0, stream>>>(ca);
}